// Round 8
// baseline (1275.278 us; speedup 1.0000x reference)
//
#include <hip/hip_runtime.h>
#include <stdint.h>

// ---------------------------------------------------------------------------
// Fused concat-linear: y = x @ W^T + b, x:[8192,4096] f32, W:[12288,4096] f32,
// b:[12288]. Output = 3 chunks of [8192,4096] f32 concatenated flat.
// v9: v8's balanced read windows with the b01' register-overwrite bug fixed:
// b01' (next-tile) ds_reads issue AFTER MFMA4 (which consumes the old b01),
// exactly as v7 did. Windows: 6/6/6/(2+4post) b128/wave/phase, counted lgkm,
// three counted vmcnt drain points. Everything else = v6 skeleton.
// ---------------------------------------------------------------------------

typedef __attribute__((ext_vector_type(8))) short short8;   // 8 x bf16 (4 VGPR)
typedef __attribute__((ext_vector_type(4))) float f32x4;    // MFMA C/D

#define BM  256
#define BN  256
#define BKT 64    // K-tile depth in bf16: 8 chunks of 16 B per row

// round-to-nearest-even f32 -> bf16 (bit trick; inputs are finite normals)
__device__ __forceinline__ unsigned short f2bf(float f) {
  union { float f; unsigned u; } v; v.f = f;
  unsigned u = v.u;
  u += 0x7FFFu + ((u >> 16) & 1u);
  return (unsigned short)(u >> 16);
}

// grid-stride cast: one float4 load (16B, lane-dense) -> one uint2 store (8B)
__global__ __launch_bounds__(256)
void cast_all_f32_to_bf16(const float* __restrict__ a, unsigned long long na4,
                          unsigned short* __restrict__ oa,
                          const float* __restrict__ b, unsigned long long nb4,
                          unsigned short* __restrict__ ob) {
  const unsigned long long stride = (unsigned long long)gridDim.x * blockDim.x;
  const unsigned long long i0 = (unsigned long long)blockIdx.x * blockDim.x + threadIdx.x;
  for (unsigned long long k = i0; k < na4; k += stride) {
    float4 v = ((const float4*)a)[k];
    uint2 o;
    o.x = (unsigned)f2bf(v.x) | ((unsigned)f2bf(v.y) << 16);
    o.y = (unsigned)f2bf(v.z) | ((unsigned)f2bf(v.w) << 16);
    ((uint2*)oa)[k] = o;
  }
  for (unsigned long long k = i0; k < nb4; k += stride) {
    float4 v = ((const float4*)b)[k];
    uint2 o;
    o.x = (unsigned)f2bf(v.x) | ((unsigned)f2bf(v.y) << 16);
    o.y = (unsigned)f2bf(v.z) | ((unsigned)f2bf(v.w) << 16);
    ((uint2*)ob)[k] = o;
  }
}

__device__ __forceinline__ void gload16(const unsigned short* src, short* dst) {
  __builtin_amdgcn_global_load_lds(
      (const __attribute__((address_space(1))) unsigned int*)src,
      (__attribute__((address_space(3))) unsigned int*)dst, 16, 0, 0);
}

// ---------------------------------------------------------------------------
// 256x256 balanced-window kernel. 512 threads = 8 waves (2M x 4N), each wave
// owns a 128x64 C sub-tile (acc[8][4] f32x4). LDS: 128 KiB (1 block/CU).
//
// Per K-tile j (buffer P=j&1), 4 double-barrier phases. Read windows
// (b128/wave; pre-barrier except noted; pinned with sched_barrier):
//   ph1w: b23(4) + ahi0(2)        [cur]   lgkm(6)  MFMA1 alo x b01
//   ph2w: ahi1-3(6)               [cur]   lgkm(8)  MFMA2 alo x b23
//   ph3w: alo'0-2(6)              [next]  lgkm(6)  MFMA3 ahi x b23
//   ph4w: alo'3(2) pre ; MFMA4 ahi x b01 ; b01'(4) POST-MFMA4 [next]
//         (b01' must follow MFMA4: MFMA4 consumes the OLD b01 variables)
// Stage ledger (v2): ph1 (j+1).Bu1->P^1; ph2 (j+2).Au0->P; ph3 (j+2).Bu0->P;
// ph4 (j+2).Au1->P.
// vmcnt drains (each immediately before its phase-end barrier):
//   ph2-end vmcnt(8): lands (j+1).Au0  -> ph3w's alo' reads safe
//   ph3-end vmcnt(8): lands (j+1).Bu0  -> ph4's b01' reads safe
//   ph4-end vmcnt(6): lands (j+1).{Au1,Bu1} -> next ph1w's b23/ahi0 safe
// Steady-state outstanding at tile entry = 6 = (j+1).{Au0,Bu0,Au1}.
// lgkm ledger (in-order DS queue) verified: ph1 wait drains alo'(8)+b01'(4);
// ph2 drains b23(4); ph3 drains ahi(8).
// Region WAR: every region's reads complete (per-wave lgkm wait precedes the
// phase barrier) >=1 barrier before its overwrite is issued.
// A-unit map: alo rows = Au0 {0-63,128-191}; ahi rows = Au1 {64-127,192-255}.
// B-unit map: b01 rows = Bu0 {BR..BR+31 c Bu0}; b23 rows = Bu1.
// ---------------------------------------------------------------------------
__global__ __launch_bounds__(512, 2)
void gemm256_bias_split(const unsigned short* __restrict__ A,   // [M][K] bf16
                        const unsigned short* __restrict__ B,   // [N][K] bf16
                        const float* __restrict__ bias,         // [N]
                        float* __restrict__ out,                // 3 x [M][H]
                        int M, int N, int K, int H) {
  __shared__ short smem[2 * BM * BKT + 2 * BN * BKT];   // 128 KiB
  short* const sA0 = smem;                  // sA(buf) = sA0 + buf*BM*BKT
  short* const sB0 = smem + 2 * BM * BKT;   // sB(buf) = sB0 + buf*BN*BKT

  const int tid  = threadIdx.x;
  const int lane = tid & 63;
  const int r16  = lane & 15;
  const int q    = lane >> 4;
  const int wave = tid >> 6;
  const int wr   = wave >> 2;          // 0..1
  const int wc   = wave & 3;           // 0..3
  const int AR   = wr * 128;
  const int BR   = wc * 64;

  // ---- two-level L2-cooperative swizzle (v5, kept) ----
  const int ntx = N / BN;
  const int nwg = gridDim.x;
  const int mty = nwg / ntx;
  int bid = blockIdx.x;
  int m0, n0;
  if ((nwg & 7) == 0 && (mty & 7) == 0) {
    const int GM  = mty >> 3;          // m-panels per XCD (4 here)
    const int xcd = bid & 7;
    const int l   = bid >> 3;          // local index within XCD chunk
    const int lm  = l % GM;
    const int ln  = l / GM;            // 0..ntx-1
    m0 = (xcd * GM + lm) * BM;
    n0 = ln * BN;
  } else if ((nwg & 7) == 0) {
    const int cpx = nwg >> 3;
    const int b2  = (bid & 7) * cpx + (bid >> 3);
    n0 = (b2 % ntx) * BN;
    m0 = (b2 / ntx) * BM;
  } else {
    n0 = (bid % ntx) * BN;
    m0 = (bid / ntx) * BM;
  }

  const int NT = K / BKT;

  // ---- staging geometry (per thread): one 16B chunk per issue ----
  const int c   = tid & 7;                       // chunk within row
  const int pr  = tid >> 3;                      // 0..63
  const int csz = c ^ (pr & 7);                  // pre-swizzled source chunk
  const unsigned short* gA = A + (size_t)(m0 + pr) * K + csz * 8;
  const int prB = (pr & 31) + ((tid >> 8) << 6); // B row interleave
  const unsigned short* gB = B + (size_t)(n0 + prB) * K + csz * 8;
  const int dA = pr * 64 + c * 8;                // shorts into sA(buf)
  const int dB = prB * 64 + c * 8;
  const size_t K128 = (size_t)128 * K;

  auto stageA = [&](int buf, int kt, int u) {    // unit u: rows {64u.., 128+64u..}
    const unsigned short* s = gA + (size_t)(u * 64) * K + kt * BKT;
    short* d = sA0 + buf * (BM * BKT) + dA + u * 4096;
    gload16(s, d);
    gload16(s + K128, d + 8192);
  };
  auto stageB = [&](int buf, int kt, int u) {    // unit u: rows {32u + 64k ..}
    const unsigned short* s = gB + (size_t)(u * 32) * K + kt * BKT;
    short* d = sB0 + buf * (BN * BKT) + dB + u * 2048;
    gload16(s, d);
    gload16(s + K128, d + 8192);
  };

  // ---- ds_read geometry: frag(row = base + f*16 + r16, chunk = ks*4 + q),
  //      chunk XOR-unswizzled by (row&7) == (r16&7) ----
  const int swz  = r16 & 7;
  const int aoff = (AR + r16) * 64;
  const int boff = (BR + r16) * 64;
  const int ck0  = (q ^ swz) * 8;                // ks=0
  const int ck1  = ((4 + q) ^ swz) * 8;          // ks=1

  f32x4 acc[8][4];
#pragma unroll
  for (int i = 0; i < 8; ++i)
#pragma unroll
    for (int j = 0; j < 4; ++j) acc[i][j] = (f32x4){0.f, 0.f, 0.f, 0.f};

  // ---- prologue: stage t0 fully + t1.{Au0,Bu0,Au1}; land t0; pre-read t0 ----
  stageA(0, 0, 0); stageB(0, 0, 0); stageA(0, 0, 1); stageB(0, 0, 1);
  stageA(1, 1, 0); stageB(1, 1, 0); stageA(1, 1, 1);
  asm volatile("s_waitcnt vmcnt(6)" ::: "memory");   // t0 fully landed
  __builtin_amdgcn_s_barrier();

  short8 alo[4][2], ahi[4][2], b01[2][2], b23[2][2];

  // pre-loop windows (ph3(-1)+ph4(-1)): tile-0 alo(8) + b01(4) from buffer 0
#pragma unroll
  for (int mf = 0; mf < 4; ++mf) {
    alo[mf][0] = *(const short8*)&sA0[aoff + mf * 1024 + ck0];
    alo[mf][1] = *(const short8*)&sA0[aoff + mf * 1024 + ck1];
  }
#pragma unroll
  for (int nf = 0; nf < 2; ++nf) {
    b01[nf][0] = *(const short8*)&sB0[boff + nf * 1024 + ck0];
    b01[nf][1] = *(const short8*)&sB0[boff + nf * 1024 + ck1];
  }
  __builtin_amdgcn_sched_barrier(0);

  for (int j = 0; j < NT; ++j) {
    const int P = j & 1;
    const short* bA  = sA0 + P * (BM * BKT);
    const short* bB  = sB0 + P * (BN * BKT);
    const short* bA1 = sA0 + (P ^ 1) * (BM * BKT);
    const short* bB1 = sB0 + (P ^ 1) * (BN * BKT);
    const bool hasNext = (j + 1 < NT);

    // ===== phase 1: stage (j+1).Bu1 ; window b23(4)+ahi0(2) ; MFMA1 =====
    if (hasNext) stageB(P ^ 1, j + 1, 1);
#pragma unroll
    for (int nf = 0; nf < 2; ++nf) {
      b23[nf][0] = *(const short8*)&bB[boff + (nf + 2) * 1024 + ck0];
      b23[nf][1] = *(const short8*)&bB[boff + (nf + 2) * 1024 + ck1];
    }
    ahi[0][0] = *(const short8*)&bA[aoff + 4 * 1024 + ck0];
    ahi[0][1] = *(const short8*)&bA[aoff + 4 * 1024 + ck1];
    __builtin_amdgcn_sched_barrier(0);
    __builtin_amdgcn_s_barrier();
    asm volatile("s_waitcnt lgkmcnt(6)" ::: "memory");  // alo,b01 done
    __builtin_amdgcn_sched_barrier(0);
    __builtin_amdgcn_s_setprio(1);
#pragma unroll
    for (int mf = 0; mf < 4; ++mf)
#pragma unroll
      for (int nf = 0; nf < 2; ++nf) {
        acc[mf][nf] = __builtin_amdgcn_mfma_f32_16x16x32_bf16(alo[mf][0], b01[nf][0], acc[mf][nf], 0, 0, 0);
        acc[mf][nf] = __builtin_amdgcn_mfma_f32_16x16x32_bf16(alo[mf][1], b01[nf][1], acc[mf][nf], 0, 0, 0);
      }
    __builtin_amdgcn_s_setprio(0);
    __builtin_amdgcn_s_barrier();

    // ===== phase 2: stage (j+2).Au0 ; window ahi1-3(6) ; MFMA2 ; vmcnt(8) =====
    if (j + 2 < NT) stageA(P, j + 2, 0);
#pragma unroll
    for (int mf = 1; mf < 4; ++mf) {
      ahi[mf][0] = *(const short8*)&bA[aoff + (mf + 4) * 1024 + ck0];
      ahi[mf][1] = *(const short8*)&bA[aoff + (mf + 4) * 1024 + ck1];
    }
    __builtin_amdgcn_sched_barrier(0);
    __builtin_amdgcn_s_barrier();
    asm volatile("s_waitcnt lgkmcnt(8)" ::: "memory");  // b23 done
    __builtin_amdgcn_sched_barrier(0);
    __builtin_amdgcn_s_setprio(1);
#pragma unroll
    for (int mf = 0; mf < 4; ++mf)
#pragma unroll
      for (int nf = 0; nf < 2; ++nf) {
        acc[mf][nf + 2] = __builtin_amdgcn_mfma_f32_16x16x32_bf16(alo[mf][0], b23[nf][0], acc[mf][nf + 2], 0, 0, 0);
        acc[mf][nf + 2] = __builtin_amdgcn_mfma_f32_16x16x32_bf16(alo[mf][1], b23[nf][1], acc[mf][nf + 2], 0, 0, 0);
      }
    __builtin_amdgcn_s_setprio(0);
    // land (j+1).Au0 -> ph3 window's alo' reads safe after this barrier
    if (j < NT - 2) asm volatile("s_waitcnt vmcnt(8)" ::: "memory");
    else            asm volatile("s_waitcnt vmcnt(0)" ::: "memory");
    __builtin_amdgcn_s_barrier();

    // ===== phase 3: stage (j+2).Bu0 ; window alo'0-2(6) ; MFMA3 ; vmcnt(8) =====
    if (j + 2 < NT) stageB(P, j + 2, 0);
    if (hasNext) {
#pragma unroll
      for (int mf = 0; mf < 3; ++mf) {
        alo[mf][0] = *(const short8*)&bA1[aoff + mf * 1024 + ck0];
        alo[mf][1] = *(const short8*)&bA1[aoff + mf * 1024 + ck1];
      }
    }
    __builtin_amdgcn_sched_barrier(0);
    __builtin_amdgcn_s_barrier();
    if (hasNext) asm volatile("s_waitcnt lgkmcnt(6)" ::: "memory");  // ahi done
    else         asm volatile("s_waitcnt lgkmcnt(0)" ::: "memory");
    __builtin_amdgcn_sched_barrier(0);
    __builtin_amdgcn_s_setprio(1);
#pragma unroll
    for (int mf = 0; mf < 4; ++mf)
#pragma unroll
      for (int nf = 0; nf < 2; ++nf) {
        acc[mf + 4][nf + 2] = __builtin_amdgcn_mfma_f32_16x16x32_bf16(ahi[mf][0], b23[nf][0], acc[mf + 4][nf + 2], 0, 0, 0);
        acc[mf + 4][nf + 2] = __builtin_amdgcn_mfma_f32_16x16x32_bf16(ahi[mf][1], b23[nf][1], acc[mf + 4][nf + 2], 0, 0, 0);
      }
    __builtin_amdgcn_s_setprio(0);
    // land (j+1).Bu0 -> ph4's post-MFMA b01' reads safe after this barrier
    if (j < NT - 2) asm volatile("s_waitcnt vmcnt(8)" ::: "memory");
    else            asm volatile("s_waitcnt vmcnt(0)" ::: "memory");
    __builtin_amdgcn_s_barrier();

    // ===== phase 4: stage (j+2).Au1 ; window alo'3(2) ; MFMA4 ; b01' post ; vmcnt(6) =====
    if (j + 2 < NT) stageA(P, j + 2, 1);
    if (hasNext) {
      alo[3][0] = *(const short8*)&bA1[aoff + 3 * 1024 + ck0];
      alo[3][1] = *(const short8*)&bA1[aoff + 3 * 1024 + ck1];
    }
    __builtin_amdgcn_sched_barrier(0);
    __builtin_amdgcn_s_barrier();
    __builtin_amdgcn_s_setprio(1);
#pragma unroll
    for (int mf = 0; mf < 4; ++mf)
#pragma unroll
      for (int nf = 0; nf < 2; ++nf) {
        acc[mf + 4][nf] = __builtin_amdgcn_mfma_f32_16x16x32_bf16(ahi[mf][0], b01[nf][0], acc[mf + 4][nf], 0, 0, 0);
        acc[mf + 4][nf] = __builtin_amdgcn_mfma_f32_16x16x32_bf16(ahi[mf][1], b01[nf][1], acc[mf + 4][nf], 0, 0, 0);
      }
    __builtin_amdgcn_s_setprio(0);
    if (hasNext) {                       // b01' AFTER MFMA4 (MFMA4 used old b01)
#pragma unroll
      for (int nf = 0; nf < 2; ++nf) {
        b01[nf][0] = *(const short8*)&bB1[boff + nf * 1024 + ck0];
        b01[nf][1] = *(const short8*)&bB1[boff + nf * 1024 + ck1];
      }
    }
    __builtin_amdgcn_sched_barrier(0);   // pin b01' before vmcnt/barrier
    // land (j+1).{Au1,Bu1} -> next ph1 window's ahi0/b23 reads safe
    if (j < NT - 2) asm volatile("s_waitcnt vmcnt(6)" ::: "memory");
    else            asm volatile("s_waitcnt vmcnt(0)" ::: "memory");
    __builtin_amdgcn_s_barrier();
  }

  // ---- epilogue: LDS-transposed +bias, float4 stores (256B segments) ----
  // C element (m0+AR + mf*16+q*4+rr, n0+BR + nf*16+r16) = acc[mf][nf][rr].
  // Each wave's 64-col range lies in ONE output chunk (BR,H multiples of 64).
  float bj[4];
#pragma unroll
  for (int nf = 0; nf < 4; ++nf) bj[nf] = bias[n0 + BR + nf * 16 + r16];
  const int nb = n0 + BR;
  const int ci = nb / H;
  const int h0 = nb - ci * H;
  float* const obase = out + (size_t)ci * ((size_t)M * H) + h0;
  const int mbase = m0 + AR;
  float* const T = reinterpret_cast<float*>(smem) + wave * 4096;  // 16KB/wave

#pragma unroll
  for (int p = 0; p < 2; ++p) {
    // write half the subtile: T[row][col], row=mf*16+q*4+rr (0..63), col 0..63
#pragma unroll
    for (int mf = 0; mf < 4; ++mf)
#pragma unroll
      for (int nf = 0; nf < 4; ++nf)
#pragma unroll
        for (int rr = 0; rr < 4; ++rr)
          T[(mf * 16 + q * 4 + rr) * 64 + nf * 16 + r16] =
              acc[p * 4 + mf][nf][rr] + bj[nf];
    asm volatile("s_waitcnt lgkmcnt(0)" ::: "memory");  // wave-private region
    // read back row-major float4: inst i covers rows i*4..i*4+3, 256B/row
#pragma unroll
    for (int i = 0; i < 16; ++i) {
      const int row = i * 4 + q;
      float4 v = *(const float4*)&T[row * 64 + r16 * 4];
      *(float4*)&obase[(size_t)(mbase + p * 64 + row) * H + r16 * 4] = v;
    }
    asm volatile("s_waitcnt lgkmcnt(0)" ::: "memory");  // drain before reuse
  }
}

// ---------------------------------------------------------------------------
// Fallback (no workspace / odd shapes): 128x128 kernel, f32 inputs staged via
// VGPR round-trip with inline f32->bf16.
// ---------------------------------------------------------------------------
#define FTILE 128
#define FBK   64

__global__ __launch_bounds__(256)
void gemm_bias_split_fb(const float* __restrict__ Af32,
                        const float* __restrict__ Bf32,
                        const float* __restrict__ bias,
                        float* __restrict__ out,
                        int M, int N, int K, int H) {
  __shared__ short sA[FTILE * FBK];
  __shared__ short sB[FTILE * FBK];

  const int tid  = threadIdx.x;
  const int lane = tid & 63;
  const int r16  = lane & 15;
  const int q    = lane >> 4;
  const int wave = tid >> 6;
  const int wm   = (wave & 1) * 64;
  const int wn   = (wave >> 1) * 64;
  const int m0   = blockIdx.y * FTILE;
  const int n0   = blockIdx.x * FTILE;

  f32x4 acc[4][4];
#pragma unroll
  for (int i = 0; i < 4; ++i)
#pragma unroll
    for (int j = 0; j < 4; ++j)
      acc[i][j] = (f32x4){0.f, 0.f, 0.f, 0.f};

  for (int k0 = 0; k0 < K; k0 += FBK) {
    __syncthreads();
#pragma unroll
    for (int it = 0; it < 4; ++it) {
      const int chunk = it * 256 + tid;
      const int row   = chunk >> 3;
      const int c     = chunk & 7;
      const int cs    = c ^ (row & 7);
      const float* gA = Af32 + (size_t)(m0 + row) * K + (k0 + cs * 8);
      const float* gB = Bf32 + (size_t)(n0 + row) * K + (k0 + cs * 8);
      float4 a0 = ((const float4*)gA)[0], a1 = ((const float4*)gA)[1];
      float4 b0 = ((const float4*)gB)[0], b1 = ((const float4*)gB)[1];
      short8 va, vb;
      va[0] = (short)f2bf(a0.x); va[1] = (short)f2bf(a0.y);
      va[2] = (short)f2bf(a0.z); va[3] = (short)f2bf(a0.w);
      va[4] = (short)f2bf(a1.x); va[5] = (short)f2bf(a1.y);
      va[6] = (short)f2bf(a1.z); va[7] = (short)f2bf(a1.w);
      vb[0] = (short)f2bf(b0.x); vb[1] = (short)f2bf(b0.y);
      vb[2] = (short)f2bf(b0.z); vb[3] = (short)f2bf(b0.w);
      vb[4] = (short)f2bf(b1.x); vb[5] = (short)f2bf(b1.y);
      vb[6] = (short)f2bf(b1.z); vb[7] = (short)f2bf(b1.w);
      *(short8*)&sA[chunk * 8] = va;
      *(short8*)&sB[chunk * 8] = vb;
    }
    __syncthreads();

#pragma unroll
    for (int ks = 0; ks < 2; ++ks) {
      short8 af[4], bfr[4];
#pragma unroll
      for (int i = 0; i < 4; ++i) {
        const int row = wm + i * 16 + r16;
        const int cc  = ks * 4 + q;
        af[i] = *(const short8*)&sA[row * FBK + (cc ^ (row & 7)) * 8];
      }
#pragma unroll
      for (int j = 0; j < 4; ++j) {
        const int row = wn + j * 16 + r16;
        const int cc  = ks * 4 + q;
        bfr[j] = *(const short8*)&sB[row * FBK + (cc ^ (row & 7)) * 8];
      }
#pragma unroll
      for (int i = 0; i < 4; ++i)
#pragma unroll
        for (int j = 0; j < 4; ++j)
          acc[i][j] = __builtin_amdgcn_mfma_f32_16x16x32_bf16(
              af[i], bfr[j], acc[i][j], 0, 0, 0);
    }
  }

  float bj[4];
#pragma unroll
  for (int j = 0; j < 4; ++j) bj[j] = bias[n0 + wn + j * 16 + r16];
  const size_t chunk_elems = (size_t)M * H;
#pragma unroll
  for (int j = 0; j < 4; ++j) {
    const int n  = n0 + wn + j * 16 + r16;
    const int ci = n / H;
    const int h  = n - ci * H;
    float* obase = out + (size_t)ci * chunk_elems + h;
#pragma unroll
    for (int i = 0; i < 4; ++i) {
      const int mb = m0 + wm + i * 16 + q * 4;
#pragma unroll
      for (int rr = 0; rr < 4; ++rr) {
        obase[(size_t)(mb + rr) * H] = acc[i][j][rr] + bj[j];
      }
    }
  }
}

extern "C" void kernel_launch(void* const* d_in, const int* in_sizes, int n_in,
                              void* d_out, int out_size, void* d_ws, size_t ws_size,
                              hipStream_t stream) {
  const float* x = (const float*)d_in[0];
  const float* W = (const float*)d_in[1];
  const float* b = (const float*)d_in[2];
  float* out = (float*)d_out;

  const int N = in_sizes[2];                 // 12288
  const int K = in_sizes[1] / N;             // 4096
  const int M = in_sizes[0] / K;             // 8192 (= 4*2048)
  const int H = N / 3;                       // 4096

  const size_t nA = (size_t)M * K;
  const size_t nB = (size_t)N * K;
  const bool ws_ok = ws_size >= (nA + nB) * sizeof(unsigned short);
  const bool big   = ws_ok && (M % BM == 0) && (N % BN == 0) &&
                     (K % BKT == 0) && (K / BKT >= 4) && ((H & 63) == 0);

  if (big) {
    unsigned short* xa = (unsigned short*)d_ws;
    unsigned short* wb = xa + nA;
    cast_all_f32_to_bf16<<<2048, 256, 0, stream>>>(
        x, (unsigned long long)(nA / 4), xa,
        W, (unsigned long long)(nB / 4), wb);
    const int nblocks = (M / BM) * (N / BN); // 32 * 48 = 1536
    gemm256_bias_split<<<nblocks, 512, 0, stream>>>(xa, wb, b, out, M, N, K, H);
  } else {
    dim3 grid(N / FTILE, M / FTILE);
    gemm_bias_split_fb<<<grid, 256, 0, stream>>>(x, W, b, out, M, N, K, H);
  }
}

// Round 9
// 1222.865 us; speedup vs baseline: 1.0429x; 1.0429x over previous
//
#include <hip/hip_runtime.h>
#include <stdint.h>

// ---------------------------------------------------------------------------
// Fused concat-linear: y = x @ W^T + b, x:[8192,4096] f32, W:[12288,4096] f32,
// b:[12288]. Output = 3 chunks of [8192,4096] f32 concatenated flat.
// v10: v6 (champion, 776us gemm) with the K-loop unrolled 2 K-tiles per
// iteration with COMPILE-TIME buffer indices (m201's "2 K-tiles/iter"):
// all LDS addresses fold to base+immediate, address VALU drops. Phase /
// barrier / lgkm / vmcnt semantics byte-identical to v6. Plus m201's
// optional pre-barrier lgkmcnt(8) hint on the 12-read phase.
// ---------------------------------------------------------------------------

typedef __attribute__((ext_vector_type(8))) short short8;   // 8 x bf16 (4 VGPR)
typedef __attribute__((ext_vector_type(4))) float f32x4;    // MFMA C/D

#define BM  256
#define BN  256
#define BKT 64    // K-tile depth in bf16: 8 chunks of 16 B per row

// round-to-nearest-even f32 -> bf16 (bit trick; inputs are finite normals)
__device__ __forceinline__ unsigned short f2bf(float f) {
  union { float f; unsigned u; } v; v.f = f;
  unsigned u = v.u;
  u += 0x7FFFu + ((u >> 16) & 1u);
  return (unsigned short)(u >> 16);
}

// grid-stride cast: one float4 load (16B, lane-dense) -> one uint2 store (8B)
__global__ __launch_bounds__(256)
void cast_all_f32_to_bf16(const float* __restrict__ a, unsigned long long na4,
                          unsigned short* __restrict__ oa,
                          const float* __restrict__ b, unsigned long long nb4,
                          unsigned short* __restrict__ ob) {
  const unsigned long long stride = (unsigned long long)gridDim.x * blockDim.x;
  const unsigned long long i0 = (unsigned long long)blockIdx.x * blockDim.x + threadIdx.x;
  for (unsigned long long k = i0; k < na4; k += stride) {
    float4 v = ((const float4*)a)[k];
    uint2 o;
    o.x = (unsigned)f2bf(v.x) | ((unsigned)f2bf(v.y) << 16);
    o.y = (unsigned)f2bf(v.z) | ((unsigned)f2bf(v.w) << 16);
    ((uint2*)oa)[k] = o;
  }
  for (unsigned long long k = i0; k < nb4; k += stride) {
    float4 v = ((const float4*)b)[k];
    uint2 o;
    o.x = (unsigned)f2bf(v.x) | ((unsigned)f2bf(v.y) << 16);
    o.y = (unsigned)f2bf(v.z) | ((unsigned)f2bf(v.w) << 16);
    ((uint2*)ob)[k] = o;
  }
}

__device__ __forceinline__ void gload16(const unsigned short* src, short* dst) {
  __builtin_amdgcn_global_load_lds(
      (const __attribute__((address_space(1))) unsigned int*)src,
      (__attribute__((address_space(3))) unsigned int*)dst, 16, 0, 0);
}

// ---------------------------------------------------------------------------
// 256x256 kernel (v6 schedule; 2-K-tile literal unroll). 512 threads = 8
// waves (2M x 4N), each wave owns a 128x64 C sub-tile (acc[8][4] f32x4).
// LDS: 128 KiB (1 block/CU).
// Per K-tile j (buffer P=j&1, now a COMPILE-TIME constant via #pragma unroll
// over half=0,1), 4 phases, each {reads (in-phase); stage 1 unit; barrier;
// lgkm(0); setprio(1); 16 MFMA; setprio(0); barrier}. Read shape 12/4/8/0.
// Stage ledger: ph1 (j+1).Bu1->P^1; ph2 (j+2).Au0->P; ph3 (j+2).Bu0->P;
// ph4 (j+2).Au1->P. One vmcnt(6) per K-tile at ph4-end (drains exactly tile
// j+1's 8 loads; 14 outstanding max); vmcnt(0) on the last two tiles.
// ---------------------------------------------------------------------------
__global__ __launch_bounds__(512, 2)
void gemm256_bias_split(const unsigned short* __restrict__ A,   // [M][K] bf16
                        const unsigned short* __restrict__ B,   // [N][K] bf16
                        const float* __restrict__ bias,         // [N]
                        float* __restrict__ out,                // 3 x [M][H]
                        int M, int N, int K, int H) {
  __shared__ short smem[2 * BM * BKT + 2 * BN * BKT];   // 128 KiB
  short* const sA0 = smem;                  // sA(buf) = sA0 + buf*BM*BKT
  short* const sB0 = smem + 2 * BM * BKT;   // sB(buf) = sB0 + buf*BN*BKT

  const int tid  = threadIdx.x;
  const int lane = tid & 63;
  const int r16  = lane & 15;
  const int q    = lane >> 4;
  const int wave = tid >> 6;
  const int wr   = wave >> 2;          // 0..1
  const int wc   = wave & 3;           // 0..3
  const int AR   = wr * 128;
  const int BR   = wc * 64;

  // ---- two-level L2-cooperative swizzle (v5, kept) ----
  const int ntx = N / BN;
  const int nwg = gridDim.x;
  const int mty = nwg / ntx;
  int bid = blockIdx.x;
  int m0, n0;
  if ((nwg & 7) == 0 && (mty & 7) == 0) {
    const int GM  = mty >> 3;          // m-panels per XCD (4 here)
    const int xcd = bid & 7;
    const int l   = bid >> 3;          // local index within XCD chunk
    const int lm  = l % GM;
    const int ln  = l / GM;            // 0..ntx-1
    m0 = (xcd * GM + lm) * BM;
    n0 = ln * BN;
  } else if ((nwg & 7) == 0) {
    const int cpx = nwg >> 3;
    const int b2  = (bid & 7) * cpx + (bid >> 3);
    n0 = (b2 % ntx) * BN;
    m0 = (b2 / ntx) * BM;
  } else {
    n0 = (bid % ntx) * BN;
    m0 = (bid / ntx) * BM;
  }

  const int NT = K / BKT;              // even (guarded by launcher)

  // ---- staging geometry (per thread): one 16B chunk per issue ----
  const int c   = tid & 7;                       // chunk within row
  const int pr  = tid >> 3;                      // 0..63
  const int csz = c ^ (pr & 7);                  // pre-swizzled source chunk
  const unsigned short* gA = A + (size_t)(m0 + pr) * K + csz * 8;
  const int prB = (pr & 31) + ((tid >> 8) << 6); // B row interleave
  const unsigned short* gB = B + (size_t)(n0 + prB) * K + csz * 8;
  const int dA = pr * 64 + c * 8;                // shorts into sA(buf)
  const int dB = prB * 64 + c * 8;
  const size_t K128 = (size_t)128 * K;

  auto stageA = [&](int buf, int kt, int u) {    // unit u: rows {64u.., 128+64u..}
    const unsigned short* s = gA + (size_t)(u * 64) * K + kt * BKT;
    short* d = sA0 + buf * (BM * BKT) + dA + u * 4096;
    gload16(s, d);
    gload16(s + K128, d + 8192);
  };
  auto stageB = [&](int buf, int kt, int u) {    // unit u: rows {32u + 64k ..}
    const unsigned short* s = gB + (size_t)(u * 32) * K + kt * BKT;
    short* d = sB0 + buf * (BN * BKT) + dB + u * 2048;
    gload16(s, d);
    gload16(s + K128, d + 8192);
  };

  // ---- ds_read geometry: frag(row = base + f*16 + r16, chunk = ks*4 + q),
  //      chunk XOR-unswizzled by (row&7) == (r16&7) ----
  const int swz  = r16 & 7;
  const int aoff = (AR + r16) * 64;
  const int boff = (BR + r16) * 64;
  const int ck0  = (q ^ swz) * 8;                // ks=0
  const int ck1  = ((4 + q) ^ swz) * 8;          // ks=1

  f32x4 acc[8][4];
#pragma unroll
  for (int i = 0; i < 8; ++i)
#pragma unroll
    for (int j = 0; j < 4; ++j) acc[i][j] = (f32x4){0.f, 0.f, 0.f, 0.f};

  // ---- prologue: stream t0.{Au0,Bu0,Au1,Bu1}, t1.{Au0,Bu0,Au1} ----
  stageA(0, 0, 0); stageB(0, 0, 0); stageA(0, 0, 1); stageB(0, 0, 1);
  stageA(1, 1, 0); stageB(1, 1, 0); stageA(1, 1, 1);
  asm volatile("s_waitcnt vmcnt(6)" ::: "memory");   // t0 fully landed
  __builtin_amdgcn_s_barrier();

  short8 alo[4][2], ahi[4][2], b01[2][2], b23[2][2];

  for (int jj = 0; jj < NT; jj += 2) {
#pragma unroll
    for (int half = 0; half < 2; ++half) {           // fully unrolled: P literal
      const int j = jj + half;
      const int P = half;                            // compile-time
      const short* bA = sA0 + P * (BM * BKT);
      const short* bB = sB0 + P * (BN * BKT);

      // ===== phase 1: read A m0-3 + B n0-1 ; stage (j+1).Bu1 =====
#pragma unroll
      for (int mf = 0; mf < 4; ++mf) {
        alo[mf][0] = *(const short8*)&bA[aoff + mf * 1024 + ck0];
        alo[mf][1] = *(const short8*)&bA[aoff + mf * 1024 + ck1];
      }
#pragma unroll
      for (int nf = 0; nf < 2; ++nf) {
        b01[nf][0] = *(const short8*)&bB[boff + nf * 1024 + ck0];
        b01[nf][1] = *(const short8*)&bB[boff + nf * 1024 + ck1];
      }
      if (j + 1 < NT) stageB(P ^ 1, j + 1, 1);
      asm volatile("s_waitcnt lgkmcnt(8)" ::: "memory");  // m201 pre-barrier hint
      __builtin_amdgcn_s_barrier();
      asm volatile("s_waitcnt lgkmcnt(0)" ::: "memory");
      __builtin_amdgcn_sched_barrier(0);
      __builtin_amdgcn_s_setprio(1);
#pragma unroll
      for (int mf = 0; mf < 4; ++mf)
#pragma unroll
        for (int nf = 0; nf < 2; ++nf) {
          acc[mf][nf] = __builtin_amdgcn_mfma_f32_16x16x32_bf16(alo[mf][0], b01[nf][0], acc[mf][nf], 0, 0, 0);
          acc[mf][nf] = __builtin_amdgcn_mfma_f32_16x16x32_bf16(alo[mf][1], b01[nf][1], acc[mf][nf], 0, 0, 0);
        }
      __builtin_amdgcn_s_setprio(0);
      __builtin_amdgcn_s_barrier();

      // ===== phase 2: read B n2-3 ; stage (j+2).Au0 =====
#pragma unroll
      for (int nf = 0; nf < 2; ++nf) {
        b23[nf][0] = *(const short8*)&bB[boff + (nf + 2) * 1024 + ck0];
        b23[nf][1] = *(const short8*)&bB[boff + (nf + 2) * 1024 + ck1];
      }
      if (j + 2 < NT) stageA(P, j + 2, 0);
      __builtin_amdgcn_s_barrier();
      asm volatile("s_waitcnt lgkmcnt(0)" ::: "memory");
      __builtin_amdgcn_sched_barrier(0);
      __builtin_amdgcn_s_setprio(1);
#pragma unroll
      for (int mf = 0; mf < 4; ++mf)
#pragma unroll
        for (int nf = 0; nf < 2; ++nf) {
          acc[mf][nf + 2] = __builtin_amdgcn_mfma_f32_16x16x32_bf16(alo[mf][0], b23[nf][0], acc[mf][nf + 2], 0, 0, 0);
          acc[mf][nf + 2] = __builtin_amdgcn_mfma_f32_16x16x32_bf16(alo[mf][1], b23[nf][1], acc[mf][nf + 2], 0, 0, 0);
        }
      __builtin_amdgcn_s_setprio(0);
      __builtin_amdgcn_s_barrier();

      // ===== phase 3: read A m4-7 ; stage (j+2).Bu0 =====
#pragma unroll
      for (int mf = 0; mf < 4; ++mf) {
        ahi[mf][0] = *(const short8*)&bA[aoff + (mf + 4) * 1024 + ck0];
        ahi[mf][1] = *(const short8*)&bA[aoff + (mf + 4) * 1024 + ck1];
      }
      if (j + 2 < NT) stageB(P, j + 2, 0);
      __builtin_amdgcn_s_barrier();
      asm volatile("s_waitcnt lgkmcnt(0)" ::: "memory");
      __builtin_amdgcn_sched_barrier(0);
      __builtin_amdgcn_s_setprio(1);
#pragma unroll
      for (int mf = 0; mf < 4; ++mf)
#pragma unroll
        for (int nf = 0; nf < 2; ++nf) {
          acc[mf + 4][nf + 2] = __builtin_amdgcn_mfma_f32_16x16x32_bf16(ahi[mf][0], b23[nf][0], acc[mf + 4][nf + 2], 0, 0, 0);
          acc[mf + 4][nf + 2] = __builtin_amdgcn_mfma_f32_16x16x32_bf16(ahi[mf][1], b23[nf][1], acc[mf + 4][nf + 2], 0, 0, 0);
        }
      __builtin_amdgcn_s_setprio(0);
      __builtin_amdgcn_s_barrier();

      // ===== phase 4: stage (j+2).Au1 ; MFMA (m4-7 x n0-1) ; vmcnt(6) =====
      if (j + 2 < NT) stageA(P, j + 2, 1);
      __builtin_amdgcn_s_barrier();
      __builtin_amdgcn_s_setprio(1);
#pragma unroll
      for (int mf = 0; mf < 4; ++mf)
#pragma unroll
        for (int nf = 0; nf < 2; ++nf) {
          acc[mf + 4][nf] = __builtin_amdgcn_mfma_f32_16x16x32_bf16(ahi[mf][0], b01[nf][0], acc[mf + 4][nf], 0, 0, 0);
          acc[mf + 4][nf] = __builtin_amdgcn_mfma_f32_16x16x32_bf16(ahi[mf][1], b01[nf][1], acc[mf + 4][nf], 0, 0, 0);
        }
      __builtin_amdgcn_s_setprio(0);
      if (j < NT - 2) asm volatile("s_waitcnt vmcnt(6)" ::: "memory");
      else            asm volatile("s_waitcnt vmcnt(0)" ::: "memory");
      __builtin_amdgcn_s_barrier();
    }
  }

  // ---- epilogue: LDS-transposed +bias, float4 stores (256B segments) ----
  // C element (m0+AR + mf*16+q*4+rr, n0+BR + nf*16+r16) = acc[mf][nf][rr].
  // Each wave's 64-col range lies in ONE output chunk (BR,H multiples of 64).
  float bj[4];
#pragma unroll
  for (int nf = 0; nf < 4; ++nf) bj[nf] = bias[n0 + BR + nf * 16 + r16];
  const int nb = n0 + BR;
  const int ci = nb / H;
  const int h0 = nb - ci * H;
  float* const obase = out + (size_t)ci * ((size_t)M * H) + h0;
  const int mbase = m0 + AR;
  float* const T = reinterpret_cast<float*>(smem) + wave * 4096;  // 16KB/wave

#pragma unroll
  for (int p = 0; p < 2; ++p) {
    // write half the subtile: T[row][col], row=mf*16+q*4+rr (0..63), col 0..63
#pragma unroll
    for (int mf = 0; mf < 4; ++mf)
#pragma unroll
      for (int nf = 0; nf < 4; ++nf)
#pragma unroll
        for (int rr = 0; rr < 4; ++rr)
          T[(mf * 16 + q * 4 + rr) * 64 + nf * 16 + r16] =
              acc[p * 4 + mf][nf][rr] + bj[nf];
    asm volatile("s_waitcnt lgkmcnt(0)" ::: "memory");  // wave-private region
    // read back row-major float4: inst i covers rows i*4..i*4+3, 256B/row
#pragma unroll
    for (int i = 0; i < 16; ++i) {
      const int row = i * 4 + q;
      float4 v = *(const float4*)&T[row * 64 + r16 * 4];
      *(float4*)&obase[(size_t)(mbase + p * 64 + row) * H + r16 * 4] = v;
    }
    asm volatile("s_waitcnt lgkmcnt(0)" ::: "memory");  // drain before reuse
  }
}

// ---------------------------------------------------------------------------
// Fallback (no workspace / odd shapes): 128x128 kernel, f32 inputs staged via
// VGPR round-trip with inline f32->bf16.
// ---------------------------------------------------------------------------
#define FTILE 128
#define FBK   64

__global__ __launch_bounds__(256)
void gemm_bias_split_fb(const float* __restrict__ Af32,
                        const float* __restrict__ Bf32,
                        const float* __restrict__ bias,
                        float* __restrict__ out,
                        int M, int N, int K, int H) {
  __shared__ short sA[FTILE * FBK];
  __shared__ short sB[FTILE * FBK];

  const int tid  = threadIdx.x;
  const int lane = tid & 63;
  const int r16  = lane & 15;
  const int q    = lane >> 4;
  const int wave = tid >> 6;
  const int wm   = (wave & 1) * 64;
  const int wn   = (wave >> 1) * 64;
  const int m0   = blockIdx.y * FTILE;
  const int n0   = blockIdx.x * FTILE;

  f32x4 acc[4][4];
#pragma unroll
  for (int i = 0; i < 4; ++i)
#pragma unroll
    for (int j = 0; j < 4; ++j)
      acc[i][j] = (f32x4){0.f, 0.f, 0.f, 0.f};

  for (int k0 = 0; k0 < K; k0 += FBK) {
    __syncthreads();
#pragma unroll
    for (int it = 0; it < 4; ++it) {
      const int chunk = it * 256 + tid;
      const int row   = chunk >> 3;
      const int c     = chunk & 7;
      const int cs    = c ^ (row & 7);
      const float* gA = Af32 + (size_t)(m0 + row) * K + (k0 + cs * 8);
      const float* gB = Bf32 + (size_t)(n0 + row) * K + (k0 + cs * 8);
      float4 a0 = ((const float4*)gA)[0], a1 = ((const float4*)gA)[1];
      float4 b0 = ((const float4*)gB)[0], b1 = ((const float4*)gB)[1];
      short8 va, vb;
      va[0] = (short)f2bf(a0.x); va[1] = (short)f2bf(a0.y);
      va[2] = (short)f2bf(a0.z); va[3] = (short)f2bf(a0.w);
      va[4] = (short)f2bf(a1.x); va[5] = (short)f2bf(a1.y);
      va[6] = (short)f2bf(a1.z); va[7] = (short)f2bf(a1.w);
      vb[0] = (short)f2bf(b0.x); vb[1] = (short)f2bf(b0.y);
      vb[2] = (short)f2bf(b0.z); vb[3] = (short)f2bf(b0.w);
      vb[4] = (short)f2bf(b1.x); vb[5] = (short)f2bf(b1.y);
      vb[6] = (short)f2bf(b1.z); vb[7] = (short)f2bf(b1.w);
      *(short8*)&sA[chunk * 8] = va;
      *(short8*)&sB[chunk * 8] = vb;
    }
    __syncthreads();

#pragma unroll
    for (int ks = 0; ks < 2; ++ks) {
      short8 af[4], bfr[4];
#pragma unroll
      for (int i = 0; i < 4; ++i) {
        const int row = wm + i * 16 + r16;
        const int cc  = ks * 4 + q;
        af[i] = *(const short8*)&sA[row * FBK + (cc ^ (row & 7)) * 8];
      }
#pragma unroll
      for (int j = 0; j < 4; ++j) {
        const int row = wn + j * 16 + r16;
        const int cc  = ks * 4 + q;
        bfr[j] = *(const short8*)&sB[row * FBK + (cc ^ (row & 7)) * 8];
      }
#pragma unroll
      for (int i = 0; i < 4; ++i)
#pragma unroll
        for (int j = 0; j < 4; ++j)
          acc[i][j] = __builtin_amdgcn_mfma_f32_16x16x32_bf16(
              af[i], bfr[j], acc[i][j], 0, 0, 0);
    }
  }

  float bj[4];
#pragma unroll
  for (int j = 0; j < 4; ++j) bj[j] = bias[n0 + wn + j * 16 + r16];
  const size_t chunk_elems = (size_t)M * H;
#pragma unroll
  for (int j = 0; j < 4; ++j) {
    const int n  = n0 + wn + j * 16 + r16;
    const int ci = n / H;
    const int h  = n - ci * H;
    float* obase = out + (size_t)ci * chunk_elems + h;
#pragma unroll
    for (int i = 0; i < 4; ++i) {
      const int mb = m0 + wm + i * 16 + q * 4;
#pragma unroll
      for (int rr = 0; rr < 4; ++rr) {
        obase[(size_t)(mb + rr) * H] = acc[i][j][rr] + bj[j];
      }
    }
  }
}

extern "C" void kernel_launch(void* const* d_in, const int* in_sizes, int n_in,
                              void* d_out, int out_size, void* d_ws, size_t ws_size,
                              hipStream_t stream) {
  const float* x = (const float*)d_in[0];
  const float* W = (const float*)d_in[1];
  const float* b = (const float*)d_in[2];
  float* out = (float*)d_out;

  const int N = in_sizes[2];                 // 12288
  const int K = in_sizes[1] / N;             // 4096
  const int M = in_sizes[0] / K;             // 8192 (= 4*2048)
  const int H = N / 3;                       // 4096

  const size_t nA = (size_t)M * K;
  const size_t nB = (size_t)N * K;
  const int NT = K / BKT;
  const bool ws_ok = ws_size >= (nA + nB) * sizeof(unsigned short);
  const bool big   = ws_ok && (M % BM == 0) && (N % BN == 0) &&
                     (K % BKT == 0) && (NT >= 4) && ((NT & 1) == 0) &&
                     ((H & 63) == 0);

  if (big) {
    unsigned short* xa = (unsigned short*)d_ws;
    unsigned short* wb = xa + nA;
    cast_all_f32_to_bf16<<<2048, 256, 0, stream>>>(
        x, (unsigned long long)(nA / 4), xa,
        W, (unsigned long long)(nB / 4), wb);
    const int nblocks = (M / BM) * (N / BN); // 32 * 48 = 1536
    gemm256_bias_split<<<nblocks, 512, 0, stream>>>(xa, wb, b, out, M, N, K, H);
  } else {
    dim3 grid(N / FTILE, M / FTILE);
    gemm_bias_split_fb<<<grid, 256, 0, stream>>>(x, W, b, out, M, N, K, H);
  }
}